// Round 3
// baseline (725.717 us; speedup 1.0000x reference)
//
#include <hip/hip_runtime.h>
#include <hip/hip_cooperative_groups.h>
#include <hip/hip_bf16.h>
#include <math.h>

namespace cg = cooperative_groups;

#define E 768
#define NH 12
#define HD 64
#define NTHR 256

typedef __attribute__((ext_vector_type(8))) short bf16x8;
typedef __attribute__((ext_vector_type(4))) float f32x4;

__device__ __forceinline__ unsigned short f2bf_rne(float f) {
    unsigned int u = __float_as_uint(f);
    u += 0x7FFF + ((u >> 16) & 1);   // round-to-nearest-even
    return (unsigned short)(u >> 16);
}

// ---------------------------------------------------------------------------
// Shared device helpers (used by both the cooperative mega kernel and the
// multi-kernel fallback path).
// ---------------------------------------------------------------------------

// Trilinear-sample one (b,p) point into sampled[u*E .. u*E+E), threads
// t, t+tstep, ... cooperate over the E/4 float4 channels.
__device__ __forceinline__ void sample_one(
    const float* x, const float* bcrd, const float* offs, int G,
    unsigned short* sampled, int u, int P, int fullN, int t, int tstep)
{
    int b = u / P, p = u % P;
    float gm1 = (float)(G - 1);

    float cx = bcrd[p * 3 + 0] + offs[u * 3 + 0];
    float cy = bcrd[p * 3 + 1] + offs[u * 3 + 1];
    float cz = bcrd[p * 3 + 2] + offs[u * 3 + 2];
    cx = fminf(fmaxf(cx, -1.f), 1.f);
    cy = fminf(fmaxf(cy, -1.f), 1.f);
    cz = fminf(fmaxf(cz, -1.f), 1.f);

    float ix = (cx + 1.f) * 0.5f * gm1;
    float iy = (cy + 1.f) * 0.5f * gm1;
    float iz = (cz + 1.f) * 0.5f * gm1;
    float fx = floorf(ix), fy = floorf(iy), fz = floorf(iz);
    float wx = ix - fx, wy = iy - fy, wz = iz - fz;

    int x0 = (int)fminf(fmaxf(fx,       0.f), gm1);
    int x1 = (int)fminf(fmaxf(fx + 1.f, 0.f), gm1);
    int y0 = (int)fminf(fmaxf(fy,       0.f), gm1);
    int y1 = (int)fminf(fmaxf(fy + 1.f, 0.f), gm1);
    int z0 = (int)fminf(fmaxf(fz,       0.f), gm1);
    int z1 = (int)fminf(fmaxf(fz + 1.f, 0.f), gm1);

    int tk[8];
    tk[0] = (z0 * G + y0) * G + x0;
    tk[1] = (z0 * G + y0) * G + x1;
    tk[2] = (z0 * G + y1) * G + x0;
    tk[3] = (z0 * G + y1) * G + x1;
    tk[4] = (z1 * G + y0) * G + x0;
    tk[5] = (z1 * G + y0) * G + x1;
    tk[6] = (z1 * G + y1) * G + x0;
    tk[7] = (z1 * G + y1) * G + x1;
    float wgt[8];
    wgt[0] = (1.f - wz) * (1.f - wy) * (1.f - wx);
    wgt[1] = (1.f - wz) * (1.f - wy) * wx;
    wgt[2] = (1.f - wz) * wy * (1.f - wx);
    wgt[3] = (1.f - wz) * wy * wx;
    wgt[4] = wz * (1.f - wy) * (1.f - wx);
    wgt[5] = wz * (1.f - wy) * wx;
    wgt[6] = wz * wy * (1.f - wx);
    wgt[7] = wz * wy * wx;

    const float4* xb4 = (const float4*)(x + ((size_t)b * fullN + 1) * E);
    ushort4* outp = (ushort4*)(sampled + (size_t)u * E);
    for (int c4 = t; c4 < E / 4; c4 += tstep) {
        float4 acc = {0.f, 0.f, 0.f, 0.f};
#pragma unroll
        for (int k = 0; k < 8; ++k) {
            float4 v = xb4[(size_t)tk[k] * (E / 4) + c4];
            acc.x += wgt[k] * v.x; acc.y += wgt[k] * v.y;
            acc.z += wgt[k] * v.z; acc.w += wgt[k] * v.w;
        }
        ushort4 o;
        o.x = f2bf_rne(acc.x); o.y = f2bf_rne(acc.y);
        o.z = f2bf_rne(acc.z); o.w = f2bf_rne(acc.w);
        outp[c4] = o;
    }
}

// 64x64 bf16 MFMA NT tile (m92 structure). All 4 waves of a 256-thread block
// cooperate; barriers are block-local.
template <bool OUT_BF16>
__device__ __forceinline__ void gemm64_tile(
    const unsigned short* A, const unsigned short* W,
    const float* bias, void* C,
    int N, int K, int m0, int n0,
    unsigned short* lsA, unsigned short* lsB)
{
    int wv = threadIdx.x >> 6;
    int ln = threadIdx.x & 63;
    int wm = (wv & 1) * 32;
    int wn = (wv >> 1) * 32;

    f32x4 acc[2][2] = {};

    int srow = ln >> 2;        // 0..15
    int scol = (ln & 3) * 8;   // 0,8,16,24

    for (int k0 = 0; k0 < K; k0 += 32) {
        int row = wv * 16 + srow;
        const unsigned short* ga = A + (size_t)(m0 + row) * K + k0 + scol;
        const unsigned short* gw = W + (size_t)(n0 + row) * K + k0 + scol;
        __builtin_amdgcn_global_load_lds(
            (const __attribute__((address_space(1))) unsigned int*)ga,
            (__attribute__((address_space(3))) unsigned int*)(lsA + wv * 16 * 32),
            16, 0, 0);
        __builtin_amdgcn_global_load_lds(
            (const __attribute__((address_space(1))) unsigned int*)gw,
            (__attribute__((address_space(3))) unsigned int*)(lsB + wv * 16 * 32),
            16, 0, 0);
        __syncthreads();

        int kq = (ln >> 4) * 8;
        int rsel = ln & 15;
        bf16x8 af[2], bfr[2];
#pragma unroll
        for (int i = 0; i < 2; ++i) {
            af[i]  = *(const bf16x8*)&lsA[(wm + i * 16 + rsel) * 32 + kq];
            bfr[i] = *(const bf16x8*)&lsB[(wn + i * 16 + rsel) * 32 + kq];
        }
#pragma unroll
        for (int i = 0; i < 2; ++i)
#pragma unroll
            for (int j = 0; j < 2; ++j)
                acc[i][j] = __builtin_amdgcn_mfma_f32_16x16x32_bf16(
                    af[i], bfr[j], acc[i][j], 0, 0, 0);
        __syncthreads();
    }

    int cr = (ln >> 4) * 4;
    int cc = ln & 15;
#pragma unroll
    for (int j = 0; j < 2; ++j) {
        int col = n0 + wn + j * 16 + cc;
        float bv = bias[col];
#pragma unroll
        for (int i = 0; i < 2; ++i) {
#pragma unroll
            for (int r = 0; r < 4; ++r) {
                int row = m0 + wm + i * 16 + cr + r;
                float v = acc[i][j][r] + bv;
                if (OUT_BF16)
                    ((unsigned short*)C)[(size_t)row * N + col] = f2bf_rne(v);
                else
                    ((float*)C)[(size_t)row * N + col] = v;
            }
        }
    }
}

// Wave-per-output matvec: C[u] = A[u/N,:] . W[u%N,:] + bias[u%N]
__device__ __forceinline__ void matvec_wave(
    const float* A, const float* W, const float* bias, float* C,
    int u, int N, int K, int ln)
{
    int m = u / N, n = u % N;
    const float* a = A + (size_t)m * K;
    const float* w = W + (size_t)n * K;
    float s = 0.f;
    for (int k = ln; k < K; k += 64) s += a[k] * w[k];
#pragma unroll
    for (int off = 32; off; off >>= 1) s += __shfl_down(s, off);
    if (ln == 0) C[u] = s + bias[n];
}

// Wave-per-(b,h) attention, shuffle-only, NO divergent shuffles: all 64
// lanes execute every __shfl; lanes >= P use a clamped (in-bounds) row and
// get masked to -inf afterwards.
__device__ __forceinline__ void attn_wave(
    const float* q, const float* kv, float* ctx, int u, int P, int ln)
{
    int b = u / NH, h = u % NH;
    float qd = q[(size_t)b * E + h * HD + ln];
    const float* kvb = kv + (size_t)b * P * (2 * E);

    int krow = (ln < P) ? ln : 0;                  // clamp: keep in-bounds
    const float* kr = kvb + (size_t)krow * (2 * E) + h * HD;
    float accd = 0.f;
#pragma unroll
    for (int e = 0; e < HD; ++e) accd += __shfl(qd, e) * kr[e];
    float s = (ln < P) ? accd * 0.125f : -INFINITY;

    float mx = s;
#pragma unroll
    for (int off = 32; off; off >>= 1) mx = fmaxf(mx, __shfl_xor(mx, off));
    float ex = (ln < P) ? __expf(s - mx) : 0.f;
    float den = ex;
#pragma unroll
    for (int off = 32; off; off >>= 1) den += __shfl_xor(den, off);
    float pl = ex / den;

    float acc = 0.f;
    for (int p = 0; p < P; ++p)
        acc += __shfl(pl, p) * kvb[(size_t)p * (2 * E) + E + h * HD + ln];
    ctx[(size_t)b * E + h * HD + ln] = acc;
}

// ---------------------------------------------------------------------------
// Cooperative mega kernel: whole pipeline, phases split by grid.sync().
// Grid is sized by the host from the occupancy query, so co-residency is
// guaranteed; all phase loops are grid-stride and work for any grid size.
// NOTE: out/scratch pointers intentionally NOT __restrict__ (they alias
// d_out).
// ---------------------------------------------------------------------------
__global__ __launch_bounds__(256, 2) void mega(
    const float* __restrict__ x, const float* __restrict__ bio,
    const float* __restrict__ bcrd, const float* __restrict__ offs,
    const float* __restrict__ conf,
    const float* __restrict__ spw, const float* __restrict__ spb,
    const float* __restrict__ ipw, const float* __restrict__ ipb,
    const float* __restrict__ opw, const float* __restrict__ opb,
    const int* __restrict__ gsize,
    float* out,
    unsigned short* sampled_bf, unsigned short* sproj_bf,
    unsigned short* spw_bf, unsigned short* kvw_bf,
    float* kv, float* q, float* ctx, float* aout,
    int B, int P, int fullN)
{
    cg::grid_group grid = cg::this_grid();

    __shared__ unsigned short lsA[64 * 32];
    __shared__ unsigned short lsB[64 * 32];

    const int bid  = blockIdx.x;
    const int t    = threadIdx.x;
    const int nblk = gridDim.x;
    const int tid  = bid * NTHR + t;
    const int nthr = nblk * NTHR;
    const int wid  = tid >> 6;
    const int nwav = nthr >> 6;
    const int ln   = t & 63;
    const int M    = B * P;

    // ---------------- Phase A: convs + q-proj + sampling (independent) -----
    for (int i = tid; i < E * E / 4; i += nthr) {
        float4 v = ((const float4*)spw)[i];
        ushort4 o;
        o.x = f2bf_rne(v.x); o.y = f2bf_rne(v.y);
        o.z = f2bf_rne(v.z); o.w = f2bf_rne(v.w);
        ((ushort4*)spw_bf)[i] = o;
    }
    for (int i = tid; i < 2 * E * E / 4; i += nthr) {
        float4 v = ((const float4*)(ipw + (size_t)E * E))[i];
        ushort4 o;
        o.x = f2bf_rne(v.x); o.y = f2bf_rne(v.y);
        o.z = f2bf_rne(v.z); o.w = f2bf_rne(v.w);
        ((ushort4*)kvw_bf)[i] = o;
    }
    for (int u = wid; u < B * E; u += nwav)
        matvec_wave(bio, ipw, ipb, q, u, E, E, ln);   // q = bio @ Wq^T + bq
    {
        int G = *gsize;
        for (int u = bid; u < M; u += nblk)
            sample_one(x, bcrd, offs, G, sampled_bf, u, P, fullN, t, NTHR);
    }

    grid.sync();

    // ---------------- Phase B: sproj = sampled @ spw^T + spb (bf16 out) ----
    {
        const int ntN = E / 64;                  // 12
        const int ntiles = (M / 64) * ntN;       // 384
        for (int u = bid; u < ntiles; u += nblk)
            gemm64_tile<true>(sampled_bf, spw_bf, spb, sproj_bf,
                              E, E, (u / ntN) * 64, (u % ntN) * 64, lsA, lsB);
    }

    grid.sync();

    // ---------------- Phase C: kv = sproj @ [Wk;Wv]^T + b (fp32 out) -------
    {
        const int ntN = 2 * E / 64;              // 24
        const int ntiles = (M / 64) * ntN;       // 768
        for (int u = bid; u < ntiles; u += nblk)
            gemm64_tile<false>(sproj_bf, kvw_bf, ipb + E, kv,
                               2 * E, E, (u / ntN) * 64, (u % ntN) * 64, lsA, lsB);
    }

    grid.sync();

    // ---------------- Phase D: attention (wave per (b,h)) ------------------
    for (int u = wid; u < B * NH; u += nwav)
        attn_wave(q, kv, ctx, u, P, ln);

    grid.sync();

    // ---------------- Phase E: aout = ctx @ opw^T + opb --------------------
    for (int u = wid; u < B * E; u += nwav)
        matvec_wave(ctx, opw, opb, aout, u, E, E, ln);

    grid.sync();

    // ---------------- Phase F: out[b,n,:] = aout[b,:] * conf[b] ------------
    {
        int pc = fullN * E / 4;
        for (int b = 0; b < B; ++b) {
            float cf = conf[b];
            const float4* ao = (const float4*)(aout + (size_t)b * E);
            float4* ob = (float4*)(out + (size_t)b * fullN * E);
            for (int i = tid; i < pc; i += nthr) {
                int c4 = i % (E / 4);
                float4 v = ao[c4];
                v.x *= cf; v.y *= cf; v.z *= cf; v.w *= cf;
                ob[i] = v;
            }
        }
    }
}

// ---------------------------------------------------------------------------
// Fallback path (R1's proven kernels) — used only if the cooperative launch
// is rejected by the runtime.
// ---------------------------------------------------------------------------
__global__ __launch_bounds__(256) void fused_conv_sample(
    const float* __restrict__ spw, const float* __restrict__ ipw,
    const float* __restrict__ x,
    const float* __restrict__ bcrd, const float* __restrict__ offs,
    const int* __restrict__ gsize,
    const float* __restrict__ bio, const float* __restrict__ ipb,
    unsigned short* __restrict__ spw_bf, unsigned short* __restrict__ kvw_bf,
    unsigned short* __restrict__ sampled, float* __restrict__ qout,
    int B, int P, int fullN, int nb_conv1, int nb_conv2)
{
    int blk = blockIdx.x;
    int t = threadIdx.x;

    if (blk < nb_conv1) {
        int i = blk * 256 + t;
        float4 v = ((const float4*)spw)[i];
        ushort4 o;
        o.x = f2bf_rne(v.x); o.y = f2bf_rne(v.y);
        o.z = f2bf_rne(v.z); o.w = f2bf_rne(v.w);
        ((ushort4*)spw_bf)[i] = o;
        return;
    }
    blk -= nb_conv1;
    if (blk < nb_conv2) {
        int i = blk * 256 + t;
        float4 v = ((const float4*)(ipw + (size_t)E * E))[i];
        ushort4 o;
        o.x = f2bf_rne(v.x); o.y = f2bf_rne(v.y);
        o.z = f2bf_rne(v.z); o.w = f2bf_rne(v.w);
        ((ushort4*)kvw_bf)[i] = o;
        return;
    }
    blk -= nb_conv2;
    if (blk < B * P) {
        sample_one(x, bcrd, offs, *gsize, sampled, blk, P, fullN, t, 256);
        return;
    }
    blk -= B * P;
    {
        int u = blk * 4 + (t >> 6);
        if (u < B * E) matvec_wave(bio, ipw, ipb, qout, u, E, E, t & 63);
    }
}

template <bool OUT_BF16>
__global__ __launch_bounds__(256) void gemm64_bf16_nt(
    const unsigned short* __restrict__ A,
    const unsigned short* __restrict__ W,
    const float* __restrict__ bias,
    void* __restrict__ C,
    int M, int N, int K)
{
    __shared__ unsigned short lsA[64 * 32];
    __shared__ unsigned short lsB[64 * 32];
    gemm64_tile<OUT_BF16>(A, W, bias, C, N, K,
                          blockIdx.y * 64, blockIdx.x * 64, lsA, lsB);
}

__global__ void attn_fb(const float* __restrict__ q,
                        const float* __restrict__ kv,
                        float* __restrict__ ctx, int B, int P)
{
    int u = blockIdx.x * 4 + (threadIdx.x >> 6);
    if (u < B * NH) attn_wave(q, kv, ctx, u, P, threadIdx.x & 63);
}

__global__ void matvec_fb(const float* __restrict__ A,
                          const float* __restrict__ W,
                          const float* __restrict__ bias,
                          float* __restrict__ C, int M, int N, int K)
{
    int u = blockIdx.x * 4 + (threadIdx.x >> 6);
    if (u < M * N) matvec_wave(A, W, bias, C, u, N, K, threadIdx.x & 63);
}

__global__ void bcast_kernel(const float* __restrict__ attn_out,
                             const float* __restrict__ conf,
                             float* __restrict__ out,
                             int fullN, int pc)
{
    int b = blockIdx.y;
    float cf = conf[b];
    const float4* ao = (const float4*)(attn_out + (size_t)b * E);
    float4* ob = (float4*)(out + (size_t)b * fullN * E);
    int i = blockIdx.x * blockDim.x + threadIdx.x;
    if (i < pc) {
        int c4 = i % (E / 4);
        float4 v = ao[c4];
        v.x *= cf; v.y *= cf; v.z *= cf; v.w *= cf;
        ob[i] = v;
    }
}

// ---------------------------------------------------------------------------
extern "C" void kernel_launch(void* const* d_in, const int* in_sizes, int n_in,
                              void* d_out, int out_size, void* d_ws, size_t ws_size,
                              hipStream_t stream)
{
    const float* x      = (const float*)d_in[0];
    const float* bio    = (const float*)d_in[1];
    const float* bcrd   = (const float*)d_in[2];
    const float* offs   = (const float*)d_in[3];
    const float* conf   = (const float*)d_in[4];
    const float* spw    = (const float*)d_in[5];
    const float* spb    = (const float*)d_in[6];
    const float* ipw    = (const float*)d_in[7];
    const float* ipb    = (const float*)d_in[8];
    const float* opw    = (const float*)d_in[9];
    const float* opb    = (const float*)d_in[10];
    const int*   gsize  = (const int*)d_in[11];
    float* out = (float*)d_out;

    int B     = in_sizes[1] / E;            // 64
    int P     = in_sizes[2] / 3;            // 32
    int fullN = in_sizes[0] / (B * E);      // 513
    int M     = B * P;                      // 2048

    // Scratch in d_out's front (~22.8 of 100.8 MB); final bcast phase
    // overwrites all of d_out last, after every read of the scratch regions.
    char* base = (char*)d_out;
    unsigned short* sampled_bf = (unsigned short*)(base + 0);          // 3.0 MB
    unsigned short* sproj_bf   = (unsigned short*)(base + 3145728);    // 3.0 MB
    unsigned short* spw_bf     = (unsigned short*)(base + 6291456);    // 1.125 MB
    unsigned short* kvw_bf     = (unsigned short*)(base + 7471104);    // 2.25 MB
    float*          kv         = (float*)(base + 9830400);             // 12.6 MB
    float*          q          = (float*)(base + 22413312);            // 192 KB
    float*          ctx        = (float*)(base + 22609920);            // 192 KB
    float*          aout       = (float*)d_ws;                         // 192 KB

    // ---- try the cooperative single-kernel path (occupancy-validated) ----
    bool coop_done = false;
    int maxBlocksPerCU = 0;
    hipError_t oe = hipOccupancyMaxActiveBlocksPerMultiprocessor(
        &maxBlocksPerCU, (const void*)mega, NTHR, 0);
    if (oe == hipSuccess && maxBlocksPerCU >= 1) {
        int nblk = maxBlocksPerCU * 256;          // 256 CUs on MI355X
        if (nblk > 768) nblk = 768;
        void* kargs[] = {
            (void*)&x, (void*)&bio, (void*)&bcrd, (void*)&offs, (void*)&conf,
            (void*)&spw, (void*)&spb, (void*)&ipw, (void*)&ipb, (void*)&opw,
            (void*)&opb, (void*)&gsize, (void*)&out,
            (void*)&sampled_bf, (void*)&sproj_bf, (void*)&spw_bf, (void*)&kvw_bf,
            (void*)&kv, (void*)&q, (void*)&ctx, (void*)&aout,
            (void*)&B, (void*)&P, (void*)&fullN
        };
        hipError_t le = hipLaunchCooperativeKernel(
            (const void*)mega, dim3(nblk), dim3(NTHR), kargs, 0, stream);
        if (le == hipSuccess) {
            coop_done = true;
        } else {
            (void)hipGetLastError();   // clear sticky error
        }
    } else {
        (void)hipGetLastError();
    }

    if (coop_done) return;

    // ---- fallback: proven R1 multi-kernel path ----
    int nb_conv1 = (E * E) / 1024;        // 576
    int nb_conv2 = (2 * E * E) / 1024;    // 1152
    int nb_q     = (B * E + 3) / 4;
    int nblocks  = nb_conv1 + nb_conv2 + M + nb_q;
    fused_conv_sample<<<nblocks, 256, 0, stream>>>(spw, ipw, x, bcrd, offs, gsize,
                                                   bio, ipb,
                                                   spw_bf, kvw_bf, sampled_bf, q,
                                                   B, P, fullN, nb_conv1, nb_conv2);
    gemm64_bf16_nt<true><<<dim3(E / 64, M / 64), 256, 0, stream>>>(
        sampled_bf, spw_bf, spb, sproj_bf, M, E, E);
    gemm64_bf16_nt<false><<<dim3(2 * E / 64, M / 64), 256, 0, stream>>>(
        sproj_bf, kvw_bf, ipb + E, kv, M, 2 * E, E);
    attn_fb<<<(B * NH + 3) / 4, 256, 0, stream>>>(q, kv, ctx, B, P);
    matvec_fb<<<(B * E + 3) / 4, 256, 0, stream>>>(ctx, opw, opb, aout, B, E, E);
    int pc = fullN * E / 4;
    bcast_kernel<<<dim3((pc + 255) / 256, B), 256, 0, stream>>>(aout, conf, out, fullN, pc);
}

// Round 4
// 393.862 us; speedup vs baseline: 1.8426x; 1.8426x over previous
//
#include <hip/hip_runtime.h>
#include <hip/hip_bf16.h>
#include <math.h>

#define E 768
#define NH 12
#define HD 64
#define NTHR 256

typedef __attribute__((ext_vector_type(8))) short bf16x8;
typedef __attribute__((ext_vector_type(4))) float f32x4;

__device__ __forceinline__ unsigned short f2bf_rne(float f) {
    unsigned int u = __float_as_uint(f);
    u += 0x7FFF + ((u >> 16) & 1);   // round-to-nearest-even
    return (unsigned short)(u >> 16);
}

// ---------------------------------------------------------------------------
// Trilinear sample of one (b,p) point -> sampled[u*E..), bf16. (R3-verified)
// ---------------------------------------------------------------------------
__device__ __forceinline__ void sample_one(
    const float* x, const float* bcrd, const float* offs, int G,
    unsigned short* sampled, int u, int P, int fullN, int t, int tstep)
{
    int b = u / P, p = u % P;
    float gm1 = (float)(G - 1);

    float cx = bcrd[p * 3 + 0] + offs[u * 3 + 0];
    float cy = bcrd[p * 3 + 1] + offs[u * 3 + 1];
    float cz = bcrd[p * 3 + 2] + offs[u * 3 + 2];
    cx = fminf(fmaxf(cx, -1.f), 1.f);
    cy = fminf(fmaxf(cy, -1.f), 1.f);
    cz = fminf(fmaxf(cz, -1.f), 1.f);

    float ix = (cx + 1.f) * 0.5f * gm1;
    float iy = (cy + 1.f) * 0.5f * gm1;
    float iz = (cz + 1.f) * 0.5f * gm1;
    float fx = floorf(ix), fy = floorf(iy), fz = floorf(iz);
    float wx = ix - fx, wy = iy - fy, wz = iz - fz;

    int x0 = (int)fminf(fmaxf(fx,       0.f), gm1);
    int x1 = (int)fminf(fmaxf(fx + 1.f, 0.f), gm1);
    int y0 = (int)fminf(fmaxf(fy,       0.f), gm1);
    int y1 = (int)fminf(fmaxf(fy + 1.f, 0.f), gm1);
    int z0 = (int)fminf(fmaxf(fz,       0.f), gm1);
    int z1 = (int)fminf(fmaxf(fz + 1.f, 0.f), gm1);

    int tk[8];
    tk[0] = (z0 * G + y0) * G + x0;
    tk[1] = (z0 * G + y0) * G + x1;
    tk[2] = (z0 * G + y1) * G + x0;
    tk[3] = (z0 * G + y1) * G + x1;
    tk[4] = (z1 * G + y0) * G + x0;
    tk[5] = (z1 * G + y0) * G + x1;
    tk[6] = (z1 * G + y1) * G + x0;
    tk[7] = (z1 * G + y1) * G + x1;
    float wgt[8];
    wgt[0] = (1.f - wz) * (1.f - wy) * (1.f - wx);
    wgt[1] = (1.f - wz) * (1.f - wy) * wx;
    wgt[2] = (1.f - wz) * wy * (1.f - wx);
    wgt[3] = (1.f - wz) * wy * wx;
    wgt[4] = wz * (1.f - wy) * (1.f - wx);
    wgt[5] = wz * (1.f - wy) * wx;
    wgt[6] = wz * wy * (1.f - wx);
    wgt[7] = wz * wy * wx;

    const float4* xb4 = (const float4*)(x + ((size_t)b * fullN + 1) * E);
    ushort4* outp = (ushort4*)(sampled + (size_t)u * E);
    for (int c4 = t; c4 < E / 4; c4 += tstep) {
        float4 acc = {0.f, 0.f, 0.f, 0.f};
#pragma unroll
        for (int k = 0; k < 8; ++k) {
            float4 v = xb4[(size_t)tk[k] * (E / 4) + c4];
            acc.x += wgt[k] * v.x; acc.y += wgt[k] * v.y;
            acc.z += wgt[k] * v.z; acc.w += wgt[k] * v.w;
        }
        ushort4 o;
        o.x = f2bf_rne(acc.x); o.y = f2bf_rne(acc.y);
        o.z = f2bf_rne(acc.z); o.w = f2bf_rne(acc.w);
        outp[c4] = o;
    }
}

// ---------------------------------------------------------------------------
// 64x64 bf16 MFMA NT tile, fp32 out (R3-verified structure).
// C[m0+..][n0+..] = A[m,:].W[n,:] + bias[n]; A,W bf16 row-major stride K.
// ---------------------------------------------------------------------------
__device__ __forceinline__ void gemm64_tile(
    const unsigned short* A, const unsigned short* W,
    const float* bias, float* C,
    int N, int K, int m0, int n0,
    unsigned short* lsA, unsigned short* lsB)
{
    int wv = threadIdx.x >> 6;
    int ln = threadIdx.x & 63;
    int wm = (wv & 1) * 32;
    int wn = (wv >> 1) * 32;

    f32x4 acc[2][2] = {};

    int srow = ln >> 2;        // 0..15
    int scol = (ln & 3) * 8;   // 0,8,16,24

    for (int k0 = 0; k0 < K; k0 += 32) {
        int row = wv * 16 + srow;
        const unsigned short* ga = A + (size_t)(m0 + row) * K + k0 + scol;
        const unsigned short* gw = W + (size_t)(n0 + row) * K + k0 + scol;
        __builtin_amdgcn_global_load_lds(
            (const __attribute__((address_space(1))) unsigned int*)ga,
            (__attribute__((address_space(3))) unsigned int*)(lsA + wv * 16 * 32),
            16, 0, 0);
        __builtin_amdgcn_global_load_lds(
            (const __attribute__((address_space(1))) unsigned int*)gw,
            (__attribute__((address_space(3))) unsigned int*)(lsB + wv * 16 * 32),
            16, 0, 0);
        __syncthreads();

        int kq = (ln >> 4) * 8;
        int rsel = ln & 15;
        bf16x8 af[2], bfr[2];
#pragma unroll
        for (int i = 0; i < 2; ++i) {
            af[i]  = *(const bf16x8*)&lsA[(wm + i * 16 + rsel) * 32 + kq];
            bfr[i] = *(const bf16x8*)&lsB[(wn + i * 16 + rsel) * 32 + kq];
        }
#pragma unroll
        for (int i = 0; i < 2; ++i)
#pragma unroll
            for (int j = 0; j < 2; ++j)
                acc[i][j] = __builtin_amdgcn_mfma_f32_16x16x32_bf16(
                    af[i], bfr[j], acc[i][j], 0, 0, 0);
        __syncthreads();
    }

    int cr = (ln >> 4) * 4;
    int cc = ln & 15;
#pragma unroll
    for (int j = 0; j < 2; ++j) {
        int col = n0 + wn + j * 16 + cc;
        float bv = bias[col];
#pragma unroll
        for (int i = 0; i < 2; ++i) {
#pragma unroll
            for (int r = 0; r < 4; ++r) {
                int row = m0 + wm + i * 16 + cr + r;
                C[(size_t)row * N + col] = acc[i][j][r] + bv;
            }
        }
    }
}

// ---------------------------------------------------------------------------
// W2 tile: W2[n0+64)[k0+64) = Wkv[n,:] @ spw[:,k], bf16 out, fp32 inputs
// staged inline (reg-convert + LDS; B-side transposed during stage).
// lsA rows = n (Wkv rows), lsB rows = k (spw cols), K-dim = j (32/step).
// ---------------------------------------------------------------------------
__device__ __forceinline__ void w2_tile(
    const float* Wkv, const float* spw, unsigned short* w2_bf,
    int n0, int k0, unsigned short* lsA, unsigned short* lsB)
{
    int t = threadIdx.x;
    int wv = t >> 6;
    int ln = t & 63;
    int wm = (wv & 1) * 32;
    int wn = (wv >> 1) * 32;

    f32x4 acc[2][2] = {};

    for (int j0 = 0; j0 < E; j0 += 32) {
        // A: lsA[r][c] = bf(Wkv[n0+r][j0+c])  (coalesced float4 loads)
#pragma unroll
        for (int rep = 0; rep < 2; ++rep) {
            int fi = t + rep * 256;
            int r = fi >> 3, c4 = fi & 7;
            float4 v = *(const float4*)(Wkv + (size_t)(n0 + r) * E + j0 + c4 * 4);
            ushort4 o;
            o.x = f2bf_rne(v.x); o.y = f2bf_rne(v.y);
            o.z = f2bf_rne(v.z); o.w = f2bf_rne(v.w);
            *(ushort4*)(lsA + r * 32 + c4 * 4) = o;
        }
        // B (transposing): lsB[kk][j] = bf(spw[j0+j][k0+kk])
#pragma unroll
        for (int rep = 0; rep < 2; ++rep) {
            int fi = t + rep * 256;
            int kk = fi >> 3, j4 = fi & 7;
            const float* sp = spw + (size_t)(j0 + j4 * 4) * E + k0 + kk;
            ushort4 o;
            o.x = f2bf_rne(sp[0 * E]);
            o.y = f2bf_rne(sp[1 * E]);
            o.z = f2bf_rne(sp[2 * E]);
            o.w = f2bf_rne(sp[3 * E]);
            *(ushort4*)(lsB + kk * 32 + j4 * 4) = o;
        }
        __syncthreads();

        int kq = (ln >> 4) * 8;
        int rsel = ln & 15;
        bf16x8 af[2], bfr[2];
#pragma unroll
        for (int i = 0; i < 2; ++i) {
            af[i]  = *(const bf16x8*)&lsA[(wm + i * 16 + rsel) * 32 + kq];
            bfr[i] = *(const bf16x8*)&lsB[(wn + i * 16 + rsel) * 32 + kq];
        }
#pragma unroll
        for (int i = 0; i < 2; ++i)
#pragma unroll
            for (int j = 0; j < 2; ++j)
                acc[i][j] = __builtin_amdgcn_mfma_f32_16x16x32_bf16(
                    af[i], bfr[j], acc[i][j], 0, 0, 0);
        __syncthreads();
    }

    int cr = (ln >> 4) * 4;
    int cc = ln & 15;
#pragma unroll
    for (int j = 0; j < 2; ++j) {
        int col = k0 + wn + j * 16 + cc;
#pragma unroll
        for (int i = 0; i < 2; ++i) {
#pragma unroll
            for (int r = 0; r < 4; ++r) {
                int row = n0 + wm + i * 16 + cr + r;
                w2_bf[(size_t)row * E + col] = f2bf_rne(acc[i][j][r]);
            }
        }
    }
}

// Wave-per-output matvec: C[u] = A[u/N,:] . W[u%N,:] + bias[u%N]  (verified)
__device__ __forceinline__ void matvec_wave(
    const float* A, const float* W, const float* bias, float* C,
    int u, int N, int K, int ln)
{
    int m = u / N, n = u % N;
    const float* a = A + (size_t)m * K;
    const float* w = W + (size_t)n * K;
    float s = 0.f;
    for (int k = ln; k < K; k += 64) s += a[k] * w[k];
#pragma unroll
    for (int off = 32; off; off >>= 1) s += __shfl_down(s, off);
    if (ln == 0) C[u] = s + bias[n];
}

// ---------------------------------------------------------------------------
// K1 "prep": sampling + W2 GEMM + q-proj + b2, all independent segments.
// ---------------------------------------------------------------------------
__global__ __launch_bounds__(256) void prep_kernel(
    const float* __restrict__ x,
    const float* __restrict__ bcrd, const float* __restrict__ offs,
    const int* __restrict__ gsize,
    const float* __restrict__ bio,
    const float* __restrict__ spw, const float* __restrict__ spb,
    const float* __restrict__ ipw, const float* __restrict__ ipb,
    unsigned short* __restrict__ sampled_bf, unsigned short* __restrict__ w2_bf,
    float* __restrict__ q, float* __restrict__ b2,
    int B, int P, int fullN, int nb_sample, int nb_w2, int nb_q)
{
    __shared__ unsigned short lsA[64 * 32];
    __shared__ unsigned short lsB[64 * 32];

    int blk = blockIdx.x;
    int t = threadIdx.x;
    int wv = t >> 6, ln = t & 63;
    const float* Wkv = ipw + (size_t)E * E;

    if (blk < nb_sample) {
        sample_one(x, bcrd, offs, *gsize, sampled_bf, blk, P, fullN, t, NTHR);
        return;
    }
    blk -= nb_sample;
    if (blk < nb_w2) {
        // 24 n-tiles x 12 k-tiles
        w2_tile(Wkv, spw, w2_bf, (blk / 12) * 64, (blk % 12) * 64, lsA, lsB);
        return;
    }
    blk -= nb_w2;
    if (blk < nb_q) {
        int u = blk * 4 + wv;
        if (u < B * E) matvec_wave(bio, ipw, ipb, q, u, E, E, ln);
        return;
    }
    blk -= nb_q;
    {
        // b2[u] = Wkv[u,:].spb + bkv[u]   (u < 1536)
        int u = blk * 4 + wv;
        if (u < 2 * E) matvec_wave(spb, Wkv, ipb + E, b2, u, 2 * E, E, ln);
    }
}

// ---------------------------------------------------------------------------
// K2: kv = sampled_bf @ W2^T + b2   (2048 x 1536, K=768, fp32 out)
// ---------------------------------------------------------------------------
__global__ __launch_bounds__(256) void kv_gemm(
    const unsigned short* __restrict__ A,
    const unsigned short* __restrict__ W,
    const float* __restrict__ bias,
    float* __restrict__ C, int N, int K)
{
    __shared__ unsigned short lsA[64 * 32];
    __shared__ unsigned short lsB[64 * 32];
    gemm64_tile(A, W, bias, C, N, K, blockIdx.y * 64, blockIdx.x * 64, lsA, lsB);
}

// ---------------------------------------------------------------------------
// K3 "tail" (path A): 8 blocks per batch. Each block: redundant attention
// for its batch (ctx -> LDS), out-proj for its 96-col slice, then writes
// out[b, :, slice] * conf[b]. Never reads d_out -> kv/q/b2 live in d_ws.
// ---------------------------------------------------------------------------
__global__ __launch_bounds__(256) void tail_kernel(
    const float* __restrict__ q, const float* __restrict__ kv,
    const float* __restrict__ opw, const float* __restrict__ opb,
    const float* __restrict__ conf, float* __restrict__ out,
    int B, int P, int fullN)
{
    __shared__ float ctx_lds[E];
    __shared__ float aout_lds[96];

    int b = blockIdx.x % B;       // b % 8 == blockIdx.x % 8 -> XCD-local kv
    int g = blockIdx.x / B;       // 0..7 column slice
    int t = threadIdx.x, wv = t >> 6, ln = t & 63;

    const float* kvb = kv + (size_t)b * P * (2 * E);

    // attention: wave wv handles heads wv, wv+4, wv+8
    for (int h = wv; h < NH; h += 4) {
        float qd = q[(size_t)b * E + h * HD + ln];
        int krow = (ln < P) ? ln : 0;
        const float* kr = kvb + (size_t)krow * (2 * E) + h * HD;
        float accd = 0.f;
#pragma unroll
        for (int e = 0; e < HD; ++e) accd += __shfl(qd, e) * kr[e];
        float s = (ln < P) ? accd * 0.125f : -INFINITY;

        float mx = s;
#pragma unroll
        for (int off = 32; off; off >>= 1) mx = fmaxf(mx, __shfl_xor(mx, off));
        float ex = (ln < P) ? __expf(s - mx) : 0.f;
        float den = ex;
#pragma unroll
        for (int off = 32; off; off >>= 1) den += __shfl_xor(den, off);
        float pl = ex / den;

        float acc = 0.f;
        for (int p = 0; p < P; ++p)
            acc += __shfl(pl, p) * kvb[(size_t)p * (2 * E) + E + h * HD + ln];
        ctx_lds[h * HD + ln] = acc;
    }
    __syncthreads();

    // out-proj slice: n in [g*96, g*96+96), 24 dots per wave
    int nbase = g * 96;
    for (int idx = 0; idx < 24; ++idx) {
        int n = nbase + wv * 24 + idx;
        const float* w = opw + (size_t)n * E;
        float s = 0.f;
        for (int k = ln; k < E; k += 64) s += ctx_lds[k] * w[k];
#pragma unroll
        for (int off = 32; off; off >>= 1) s += __shfl_down(s, off);
        if (ln == 0) aout_lds[wv * 24 + idx] = s + opb[n];
    }
    __syncthreads();

    // broadcast slice: out[b, row, nbase..nbase+96) = aout * conf[b]
    float cf = conf[b];
    const float4* a4 = (const float4*)aout_lds;
    float* ob = out + (size_t)b * fullN * E + nbase;
    int tot = fullN * 24;
    for (int i = t; i < tot; i += NTHR) {
        int row = i / 24, c4 = i % 24;
        float4 v = a4[c4];
        v.x *= cf; v.y *= cf; v.z *= cf; v.w *= cf;
        *(float4*)(ob + (size_t)row * E + c4 * 4) = v;
    }
}

// ---------------------------------------------------------------------------
// Path-B tail (fallback if d_ws is too small): R1-proven kernels.
// ---------------------------------------------------------------------------
__global__ void attn_fb(const float* __restrict__ q,
                        const float* __restrict__ kv,
                        float* __restrict__ ctx, int B, int P)
{
    int u = blockIdx.x * 4 + (threadIdx.x >> 6);
    int ln = threadIdx.x & 63;
    if (u >= B * NH) return;
    int b = u / NH, h = u % NH;
    float qd = q[(size_t)b * E + h * HD + ln];
    const float* kvb = kv + (size_t)b * P * (2 * E);
    int krow = (ln < P) ? ln : 0;
    const float* kr = kvb + (size_t)krow * (2 * E) + h * HD;
    float accd = 0.f;
#pragma unroll
    for (int e = 0; e < HD; ++e) accd += __shfl(qd, e) * kr[e];
    float s = (ln < P) ? accd * 0.125f : -INFINITY;
    float mx = s;
#pragma unroll
    for (int off = 32; off; off >>= 1) mx = fmaxf(mx, __shfl_xor(mx, off));
    float ex = (ln < P) ? __expf(s - mx) : 0.f;
    float den = ex;
#pragma unroll
    for (int off = 32; off; off >>= 1) den += __shfl_xor(den, off);
    float pl = ex / den;
    float acc = 0.f;
    for (int p = 0; p < P; ++p)
        acc += __shfl(pl, p) * kvb[(size_t)p * (2 * E) + E + h * HD + ln];
    ctx[(size_t)b * E + h * HD + ln] = acc;
}

__global__ void matvec_fb(const float* __restrict__ A,
                          const float* __restrict__ W,
                          const float* __restrict__ bias,
                          float* __restrict__ C, int M, int N, int K)
{
    int u = blockIdx.x * 4 + (threadIdx.x >> 6);
    if (u < M * N) matvec_wave(A, W, bias, C, u, N, K, threadIdx.x & 63);
}

__global__ void bcast_kernel(const float* __restrict__ attn_out,
                             const float* __restrict__ conf,
                             float* __restrict__ out,
                             int fullN, int pc)
{
    int b = blockIdx.y;
    float cf = conf[b];
    const float4* ao = (const float4*)(attn_out + (size_t)b * E);
    float4* ob = (float4*)(out + (size_t)b * fullN * E);
    int i = blockIdx.x * blockDim.x + threadIdx.x;
    if (i < pc) {
        int c4 = i % (E / 4);
        float4 v = ao[c4];
        v.x *= cf; v.y *= cf; v.z *= cf; v.w *= cf;
        ob[i] = v;
    }
}

// ---------------------------------------------------------------------------
extern "C" void kernel_launch(void* const* d_in, const int* in_sizes, int n_in,
                              void* d_out, int out_size, void* d_ws, size_t ws_size,
                              hipStream_t stream)
{
    const float* x      = (const float*)d_in[0];
    const float* bio    = (const float*)d_in[1];
    const float* bcrd   = (const float*)d_in[2];
    const float* offs   = (const float*)d_in[3];
    const float* conf   = (const float*)d_in[4];
    const float* spw    = (const float*)d_in[5];
    const float* spb    = (const float*)d_in[6];
    const float* ipw    = (const float*)d_in[7];
    const float* ipb    = (const float*)d_in[8];
    const float* opw    = (const float*)d_in[9];
    const float* opb    = (const float*)d_in[10];
    const int*   gsize  = (const int*)d_in[11];
    float* out = (float*)d_out;

    int B     = in_sizes[1] / E;            // 64
    int P     = in_sizes[2] / 3;            // 32
    int fullN = in_sizes[0] / (B * E);      // 513
    int M     = B * P;                      // 2048

    // sampled_bf / w2_bf stay in d_out's front on both paths (only read by
    // K1/K2, and fully overwritten by the final output writes afterwards).
    char* base = (char*)d_out;
    unsigned short* sampled_bf = (unsigned short*)(base + 0);          // 3.0 MB
    unsigned short* w2_bf      = (unsigned short*)(base + 3145728);    // 2.25 MB

    const size_t kv_bytes = (size_t)M * (2 * E) * 4;        // 12,582,912
    const size_t q_bytes  = (size_t)B * E * 4;              // 196,608
    const size_t b2_bytes = (size_t)(2 * E) * 4;            // 6,144
    const bool path_a = (ws_size >= kv_bytes + q_bytes + b2_bytes);

    float *kv, *q, *b2;
    if (path_a) {
        kv = (float*)d_ws;
        q  = (float*)((char*)d_ws + kv_bytes);
        b2 = (float*)((char*)d_ws + kv_bytes + q_bytes);
    } else {
        kv = (float*)(base + 5505024);                      // 12.6 MB
        q  = (float*)(base + 18087936);                     // 192 KB
        b2 = (float*)(base + 18481152);                     // 6 KB
    }

    // K1: prep (sample + W2 GEMM + q-proj + b2)
    int nb_sample = M;                       // 2048
    int nb_w2     = (2 * E / 64) * (E / 64); // 288
    int nb_q      = (B * E + 3) / 4;         // 12288
    int nb_b2     = (2 * E + 3) / 4;         // 384
    prep_kernel<<<nb_sample + nb_w2 + nb_q + nb_b2, NTHR, 0, stream>>>(
        x, bcrd, offs, gsize, bio, spw, spb, ipw, ipb,
        sampled_bf, w2_bf, q, b2, B, P, fullN, nb_sample, nb_w2, nb_q);

    // K2: kv = sampled @ W2^T + b2
    kv_gemm<<<dim3(2 * E / 64, M / 64), NTHR, 0, stream>>>(
        sampled_bf, w2_bf, b2, kv, 2 * E, E);

    if (path_a) {
        // K3: fused attention + out-proj + broadcast (writes all of d_out)
        tail_kernel<<<B * 8, NTHR, 0, stream>>>(q, kv, opw, opb, conf, out,
                                                B, P, fullN);
    } else {
        // fallback: R1-proven tail (ctx in d_out scratch, aout in d_ws)
        float* ctx  = (float*)(base + 18284544);
        float* aout = (float*)d_ws;                          // 192 KB
        attn_fb<<<(B * NH + 3) / 4, NTHR, 0, stream>>>(q, kv, ctx, B, P);
        matvec_fb<<<(B * E + 3) / 4, NTHR, 0, stream>>>(ctx, opw, opb, aout,
                                                        B, E, E);
        int pc = fullN * E / 4;
        bcast_kernel<<<dim3((pc + 255) / 256, B), NTHR, 0, stream>>>(
            aout, conf, out, fullN, pc);
    }
}